// Round 1
// baseline (347.334 us; speedup 1.0000x reference)
//
#include <hip/hip_runtime.h>

#define N_NODES 40000
#define CCH 128
#define E_SP 320000
#define E_ALL 680000
#define MAXD 96
#define HASH_N (1u<<21)
#define HMASK (HASH_N-1u)

typedef unsigned int u32;
typedef unsigned short u16;
typedef __attribute__((ext_vector_type(8))) __bf16 bf16x8;
typedef __attribute__((ext_vector_type(4))) float f32x4;

__device__ __forceinline__ u16 f2bf(float f){
  u32 u = __builtin_bit_cast(u32, f);
  u += 0x7FFFu + ((u >> 16) & 1u);
  return (u16)(u >> 16);
}
__device__ __forceinline__ float bf2f(u16 s){
  return __builtin_bit_cast(float, (u32)s << 16);
}
__device__ __forceinline__ f32x4 mfma16(bf16x8 a, bf16x8 b, f32x4 c){
  return __builtin_amdgcn_mfma_f32_16x16x32_bf16(a, b, c, 0, 0, 0);
}

// ---------------- LN1: feats f32 -> h1 bf16 ----------------
__global__ __launch_bounds__(256) void ln1_k(const float* __restrict__ f,
    const float* __restrict__ w, const float* __restrict__ b, u16* __restrict__ o){
  int row = blockIdx.x*4 + (threadIdx.x>>6);
  int lane = threadIdx.x & 63;
  float2 v = *(const float2*)(f + (size_t)row*CCH + lane*2);
  float s = v.x + v.y;
  #pragma unroll
  for (int d=1; d<64; d<<=1) s += __shfl_xor(s, d);
  float mu = s*(1.f/CCH);
  float d0 = v.x-mu, d1 = v.y-mu;
  float q = d0*d0 + d1*d1;
  #pragma unroll
  for (int d=1; d<64; d<<=1) q += __shfl_xor(q, d);
  float is = rsqrtf(q*(1.f/CCH) + 1e-5f);
  float2 wv = *(const float2*)(w + lane*2);
  float2 bv = *(const float2*)(b + lane*2);
  u32 pk = (u32)f2bf(d0*is*wv.x + bv.x) | ((u32)f2bf(d1*is*wv.y + bv.y) << 16);
  *(u32*)(o + (size_t)row*CCH + lane*2) = pk;
}

// ---------------- weight transpose + bf16 cast ----------------
__global__ void prep_w(const float* __restrict__ qw, const float* __restrict__ pw,
                       const float* __restrict__ f1w, const float* __restrict__ f2w,
                       u16* __restrict__ wq, u16* __restrict__ wp,
                       u16* __restrict__ w1, u16* __restrict__ w2){
  int t = blockIdx.x*256 + threadIdx.x;
  if (t < 49152){ int n=t>>7, k=t&127; wq[t] = f2bf(qw[k*384+n]); return; }
  t -= 49152;
  if (t < 16384){ int n=t>>7, k=t&127; wp[t] = f2bf(pw[k*128+n]); return; }
  t -= 16384;
  if (t < 65536){ int n=t>>7, k=t&127; w1[t] = f2bf(f1w[k*512+n]); return; }
  t -= 65536;
  if (t < 65536){ int n=t>>9, k=t&511; w2[t] = f2bf(f2w[k*128+n]); return; }
}

// ---------------- edge dedup + adjacency build ----------------
__global__ void edge_build(const int* __restrict__ sp, const int* __restrict__ te,
    u32* __restrict__ htab, int* __restrict__ deg, int* __restrict__ adj){
  int e = blockIdx.x*256 + threadIdx.x;
  if (e >= E_ALL) return;
  int i, j;
  if (e < E_SP){ i = sp[e]; j = sp[E_SP+e]; }
  else if (e < 2*E_SP){ int t = e - E_SP; i = sp[E_SP+t]; j = sp[t]; }
  else { int t = e - 2*E_SP; i = te[t]; j = te[N_NODES+t]; }
  u32 key = (u32)i*40000u + (u32)j;     // < 1.6e9, fits u32, never 0xFFFFFFFF
  u32 slot = (key * 0x9E3779B1u) >> 11; // top 21 bits
  for (;;){
    u32 prev = atomicCAS(&htab[slot], 0xFFFFFFFFu, key);
    if (prev == 0xFFFFFFFFu){            // we inserted: unique representative
      int pos = atomicAdd(&deg[i], 1);
      if (pos < MAXD) adj[(size_t)i*MAXD + pos] = j;
      break;
    }
    if (prev == key) break;              // duplicate edge: drop
    slot = (slot + 1) & HMASK;
  }
}

// ---------------- attention: one wave per node ----------------
__global__ __launch_bounds__(256) void attn_k(const u16* __restrict__ qkvb,
    const int* __restrict__ deg, const int* __restrict__ adj, u16* __restrict__ x){
  int node = blockIdx.x*4 + (threadIdx.x>>6);
  int lane = threadIdx.x & 63;
  int off = (lane>>3)*16 + (lane&7)*2;   // head = lane/8, dims 2c,2c+1
  u32 qp = *(const u32*)(qkvb + (size_t)node*384 + off);
  float q0 = bf2f((u16)qp), q1 = bf2f((u16)(qp>>16));
  float m = -1e30f, s = 0.f, a0 = 0.f, a1 = 0.f;
  int d = deg[node]; if (d > MAXD) d = MAXD;
  const int* al = adj + (size_t)node*MAXD;
  for (int t=0; t<d; ++t){
    int j = al[t];
    const u16* base = qkvb + (size_t)j*384 + off;
    u32 kp = *(const u32*)(base + 128);
    u32 vp = *(const u32*)(base + 256);
    float p = q0*bf2f((u16)kp) + q1*bf2f((u16)(kp>>16));
    p += __shfl_xor(p,1); p += __shfl_xor(p,2); p += __shfl_xor(p,4);
    if (p > m){ float r = __expf(m - p); s *= r; a0 *= r; a1 *= r; m = p; }
    float e = __expf(p - m);
    s += e;
    a0 += e*bf2f((u16)vp);
    a1 += e*bf2f((u16)(vp>>16));
  }
  float inv = 1.f/s;
  u32 pk = (u32)f2bf(a0*inv) | ((u32)f2bf(a1*inv) << 16);
  *(u32*)(x + (size_t)node*CCH + off) = pk;
}

// ---------------- generic MFMA GEMM, A[M][K] bf16 @ BT[N][K] bf16 ----------------
// EPI: 0=QKV(bias, q*=0.25, ->bf16)  1=PROJ(bias+residual+LN2, ->f32 feats2 + bf16 h2)
//      2=FC1(bias+GELU ->bf16)       3=FC2(bias+residual ->f32 out)
template<int K, int N, int EPI>
__global__ __launch_bounds__(256) void gemm_k(
    const u16* __restrict__ A, const u16* __restrict__ BT,
    const float* __restrict__ bias, const float* __restrict__ res,
    const float* __restrict__ lnw, const float* __restrict__ lnb,
    float* __restrict__ outf, u16* __restrict__ outb)
{
  constexpr int KF = K/32, NT = N/16;
  const int lane = threadIdx.x & 63;
  const int lr = lane & 15, lg = lane >> 4;
  const int row0 = blockIdx.x*64 + (threadIdx.x>>6)*16;
  const u16* Ar = A + (size_t)(row0+lr)*K + lg*8;
  bf16x8 a[KF];
  #pragma unroll
  for (int kf=0; kf<KF; ++kf) a[kf] = *(const bf16x8*)(Ar + kf*32);

  if constexpr (EPI == 1){
    f32x4 acc[NT];
    #pragma unroll
    for (int t=0; t<NT; ++t){
      acc[t] = (f32x4){0.f,0.f,0.f,0.f};
      const u16* Br = BT + (size_t)(t*16+lr)*K + lg*8;
      #pragma unroll
      for (int kf=0; kf<KF; ++kf) acc[t] = mfma16(a[kf], *(const bf16x8*)(Br + kf*32), acc[t]);
    }
    float val[NT][4];
    #pragma unroll
    for (int t=0; t<NT; ++t){
      int col = t*16 + lr;
      float pb = bias[col];
      #pragma unroll
      for (int r=0; r<4; ++r){
        int row = row0 + lg*4 + r;
        float v = acc[t][r] + pb + res[(size_t)row*CCH + col];
        val[t][r] = v;
        outf[(size_t)row*CCH + col] = v;   // feats2 (pre-LN, f32)
      }
    }
    #pragma unroll
    for (int r=0; r<4; ++r){
      int row = row0 + lg*4 + r;
      float s = 0.f;
      #pragma unroll
      for (int t=0; t<NT; ++t) s += val[t][r];
      #pragma unroll
      for (int d=1; d<16; d<<=1) s += __shfl_xor(s, d);
      float mu = s*(1.f/CCH);
      float q = 0.f;
      #pragma unroll
      for (int t=0; t<NT; ++t){ float dd = val[t][r]-mu; q += dd*dd; }
      #pragma unroll
      for (int d=1; d<16; d<<=1) q += __shfl_xor(q, d);
      float is = rsqrtf(q*(1.f/CCH) + 1e-5f);
      #pragma unroll
      for (int t=0; t<NT; ++t){
        int col = t*16 + lr;
        outb[(size_t)row*CCH + col] = f2bf((val[t][r]-mu)*is*lnw[col] + lnb[col]);
      }
    }
  } else {
    for (int t=0; t<NT; ++t){
      f32x4 acc = (f32x4){0.f,0.f,0.f,0.f};
      const u16* Br = BT + (size_t)(t*16+lr)*K + lg*8;
      #pragma unroll
      for (int kf=0; kf<KF; ++kf) acc = mfma16(a[kf], *(const bf16x8*)(Br + kf*32), acc);
      int col = t*16 + lr;
      float bv = bias[col];
      #pragma unroll
      for (int r=0; r<4; ++r){
        int row = row0 + lg*4 + r;
        float v = acc[r] + bv;
        if constexpr (EPI == 0){
          if (col < CCH) v *= 0.25f;            // q * dh^-0.5
          outb[(size_t)row*N + col] = f2bf(v);
        } else if constexpr (EPI == 2){
          v = 0.5f*v*(1.f + erff(v*0.70710678118f));
          outb[(size_t)row*N + col] = f2bf(v);
        } else {
          v += res[(size_t)row*CCH + col];
          outf[(size_t)row*CCH + col] = v;
        }
      }
    }
  }
}

extern "C" void kernel_launch(void* const* d_in, const int* in_sizes, int n_in,
                              void* d_out, int out_size, void* d_ws, size_t ws_size,
                              hipStream_t stream){
  const float* feats = (const float*)d_in[0];
  const int*   te    = (const int*)d_in[2];
  const int*   sp    = (const int*)d_in[3];
  const float* n1w   = (const float*)d_in[5];
  const float* n1b   = (const float*)d_in[6];
  const float* qw    = (const float*)d_in[7];
  const float* qb    = (const float*)d_in[8];
  const float* pw    = (const float*)d_in[9];
  const float* pb    = (const float*)d_in[10];
  const float* n2w   = (const float*)d_in[11];
  const float* n2b   = (const float*)d_in[12];
  const float* f1w   = (const float*)d_in[13];
  const float* f1b   = (const float*)d_in[14];
  const float* f2w   = (const float*)d_in[15];
  const float* f2b_  = (const float*)d_in[16];
  float* out = (float*)d_out;

  char* p = (char*)d_ws;
  u16* wq = (u16*)p; p += 384*128*2;
  u16* wp = (u16*)p; p += 128*128*2;
  u16* w1 = (u16*)p; p += 512*128*2;
  u16* w2 = (u16*)p; p += 128*512*2;
  u16* h   = (u16*)p; p += (size_t)N_NODES*CCH*2;   // h1, later reused as h2
  u16* xb  = (u16*)p; p += (size_t)N_NODES*CCH*2;   // attention output (bf16)
  float* ft2 = (float*)p; p += (size_t)N_NODES*CCH*4; // feats after first residual
  char* breg = p;                                    // overlay region
  u16* qkvb = (u16*)breg;                            // 40000x384 bf16
  int* deg  = (int*)(breg + 30720000);
  int* adj  = (int*)(breg + 30720000 + 160000);
  u32* htab = (u32*)(breg + 30720000 + 160000 + 15360000);
  u16* mbuf = (u16*)breg;                            // 40000x512 bf16, overlays qkvb+deg+adj

  hipMemsetAsync(deg, 0, N_NODES*4, stream);
  hipMemsetAsync(htab, 0xFF, HASH_N*4, stream);
  prep_w<<<768, 256, 0, stream>>>(qw, pw, f1w, f2w, wq, wp, w1, w2);
  ln1_k<<<N_NODES/4, 256, 0, stream>>>(feats, n1w, n1b, h);
  edge_build<<<(E_ALL+255)/256, 256, 0, stream>>>(sp, te, htab, deg, adj);
  gemm_k<128,384,0><<<N_NODES/64, 256, 0, stream>>>(h, wq, qb, nullptr, nullptr, nullptr, nullptr, qkvb);
  attn_k<<<N_NODES/4, 256, 0, stream>>>(qkvb, deg, adj, xb);
  gemm_k<128,128,1><<<N_NODES/64, 256, 0, stream>>>(xb, wp, pb, feats, n2w, n2b, ft2, h);
  gemm_k<128,512,2><<<N_NODES/64, 256, 0, stream>>>(h, w1, f1b, nullptr, nullptr, nullptr, nullptr, mbuf);
  gemm_k<512,128,3><<<N_NODES/64, 256, 0, stream>>>(mbuf, w2, f2b_, ft2, nullptr, nullptr, out, nullptr);
}